// Round 1
// baseline (413.861 us; speedup 1.0000x reference)
//
#include <hip/hip_runtime.h>
#include <hip/hip_cooperative_groups.h>

// SparseToDense: scatter features [N,32] into dense [B=4, C=32, D=64, H=64, W=64].
// flat_idx (int32 on device) indexes B*D*H*W sites; output is NCDHW. DHW = 2^18.
//
// R8: fuse init+build+gather into ONE cooperative kernel with grid.sync()
// between phases. Rationale:
//   - removes the init_head launch + two inter-kernel gaps in the graph,
//   - __launch_bounds__(256,8) pins VGPR<=64 so the co-resident coop grid
//     runs 32 waves/CU during the gather phase (max TLP for the random
//     128B L3 reads of the chain walk),
//   - the fused dispatch (~85-95us) will rank in rocprof top-5, exposing
//     FETCH/WRITE/VALUBusy for the first time (fills dominated before).
// Kept from R7: cached loads for feats/head/next; NONTEMPORAL stores for the
// 134 MB output stream (keeps chain data resident in L2); 2 threads/site
// (pair lanes split the 128B row into 64B halves; half the acc VGPRs).
// Budget model: init ~1us + build ~19us (400k fabric atomics) + gather
// ~55-70us vs ~32us byte floor.

#define DHW_LOG2 18
#define DHW (1 << DHW_LOG2)
#define C_CH 32
#define N_SITES_TOTAL (4 * DHW)   // B=4 -> 1048576 sites

typedef float floatx4 __attribute__((ext_vector_type(4)));

namespace cg = cooperative_groups;

__global__ __launch_bounds__(256, 8) void fused_kernel(
    const float* __restrict__ feats,
    const int* __restrict__ flat_idx,
    int* __restrict__ head,
    int* __restrict__ next,
    float* __restrict__ out,
    int n_active)
{
    cg::grid_group grid = cg::this_grid();
    const int tid0 = blockIdx.x * blockDim.x + threadIdx.x;
    const int nthr = gridDim.x * blockDim.x;

    // ---- Phase A: head[:] = -1 (8B stores) ----
    int2* head2 = (int2*)head;
    for (int i = tid0; i < N_SITES_TOTAL / 2; i += nthr)
        head2[i] = make_int2(-1, -1);

    grid.sync();

    // ---- Phase B: build per-site chains (device-scope atomicExch, 4 MB head) ----
    for (int i = tid0; i < n_active; i += nthr) {
        int s = flat_idx[i];
        int prev = atomicExch(&head[s], i);
        next[i] = prev;
    }

    grid.sync();

    // ---- Phase C: gather. 2 threads per site; thread (S,h) owns channels
    // h*16..h*16+15. Grid-stride over 2*N_SITES site-halves. ----
    for (int t = tid0; t < 2 * N_SITES_TOTAL; t += nthr) {
        int S = t >> 1;        // site (lane pairs share a site)
        int h = t & 1;         // channel half

        int b  = S >> DHW_LOG2;
        int sp = S & (DHW - 1);

        floatx4 a0 = (floatx4)0.f, a1 = (floatx4)0.f, a2 = (floatx4)0.f, a3 = (floatx4)0.f;

        int p = head[S];       // pair lanes broadcast; L2-resident 4 MB
        while (p != -1) {
            const floatx4* row = (const floatx4*)(feats + ((size_t)p * C_CH + h * 16));
            int pn = next[p];                 // issue next-hop early
            floatx4 f0 = row[0];              // cached: 1 line fill + 3 L1 hits / 64B half
            floatx4 f1 = row[1];
            floatx4 f2 = row[2];
            floatx4 f3 = row[3];
            a0 += f0; a1 += f1; a2 += f2; a3 += f3;
            p = pn;
        }

        // out[(b*32 + c) << 18 | sp], c = h*16 + j. Within a wave each store
        // instr covers two 128B contiguous segments (one per channel-half).
        float* o = out + (((size_t)(b * C_CH + h * 16)) << DHW_LOG2) + sp;
        float acc[16] = {
            a0.x, a0.y, a0.z, a0.w,  a1.x, a1.y, a1.z, a1.w,
            a2.x, a2.y, a2.z, a2.w,  a3.x, a3.y, a3.z, a3.w };
        #pragma unroll
        for (int j = 0; j < 16; ++j)
            __builtin_nontemporal_store(acc[j], o + ((size_t)j << DHW_LOG2));
    }
}

// ---- non-cooperative path (R7 behavior) kept as fallback ----

__global__ __launch_bounds__(256) void init_head_kernel(int* __restrict__ head, int n)
{
    int t = blockIdx.x * blockDim.x + threadIdx.x;
    if (t < n) head[t] = -1;
}

__global__ __launch_bounds__(256) void build_chains_kernel(
    const int* __restrict__ flat_idx,
    int* __restrict__ head,
    int* __restrict__ next,
    int n_active)
{
    int i = blockIdx.x * blockDim.x + threadIdx.x;
    if (i >= n_active) return;
    int s = flat_idx[i];
    int prev = atomicExch(&head[s], i);
    next[i] = prev;
}

__global__ __launch_bounds__(256) void gather_kernel(
    const float* __restrict__ feats,
    const int* __restrict__ head,
    const int* __restrict__ next,
    float* __restrict__ out)
{
    int t = blockIdx.x * blockDim.x + threadIdx.x;
    int S = t >> 1;
    int h = t & 1;

    int b  = S >> DHW_LOG2;
    int sp = S & (DHW - 1);

    floatx4 a0 = (floatx4)0.f, a1 = (floatx4)0.f, a2 = (floatx4)0.f, a3 = (floatx4)0.f;

    int p = head[S];
    while (p != -1) {
        const floatx4* row = (const floatx4*)(feats + ((size_t)p * C_CH + h * 16));
        int pn = next[p];
        floatx4 f0 = row[0];
        floatx4 f1 = row[1];
        floatx4 f2 = row[2];
        floatx4 f3 = row[3];
        a0 += f0; a1 += f1; a2 += f2; a3 += f3;
        p = pn;
    }

    float* o = out + (((size_t)(b * C_CH + h * 16)) << DHW_LOG2) + sp;
    float acc[16] = {
        a0.x, a0.y, a0.z, a0.w,  a1.x, a1.y, a1.z, a1.w,
        a2.x, a2.y, a2.z, a2.w,  a3.x, a3.y, a3.z, a3.w };
    #pragma unroll
    for (int j = 0; j < 16; ++j)
        __builtin_nontemporal_store(acc[j], o + ((size_t)j << DHW_LOG2));
}

// ---- fallback (R3 behavior) if workspace is too small ----
__global__ __launch_bounds__(256) void zero_kernel(float4* __restrict__ out, int n4)
{
    int t = blockIdx.x * blockDim.x + threadIdx.x;
    if (t < n4) out[t] = make_float4(0.f, 0.f, 0.f, 0.f);
}

__global__ __launch_bounds__(256) void scatter_atomic_kernel(
    const float* __restrict__ feats,
    const int* __restrict__ flat_idx,
    float* __restrict__ out,
    int n_active)
{
    int t = blockIdx.x * blockDim.x + threadIdx.x;
    int i = t >> 5, c = t & 31;
    if (i >= n_active) return;
    int s = flat_idx[i];
    atomicAdd(&out[(((size_t)(s >> DHW_LOG2) * C_CH + c) << DHW_LOG2) + (s & (DHW - 1))],
              feats[(size_t)i * C_CH + c]);
}

extern "C" void kernel_launch(void* const* d_in, const int* in_sizes, int n_in,
                              void* d_out, int out_size, void* d_ws, size_t ws_size,
                              hipStream_t stream) {
    const float* feats = (const float*)d_in[0];
    const int*   idx   = (const int*)d_in[1];
    float*       out   = (float*)d_out;
    int n_active = in_sizes[1];   // 400000

    size_t head_bytes = (size_t)N_SITES_TOTAL * sizeof(int);      // 4 MB
    size_t next_bytes = (size_t)n_active * sizeof(int);           // 1.6 MB

    if (ws_size >= head_bytes + next_bytes) {
        int* head = (int*)d_ws;
        int* next = (int*)((char*)d_ws + head_bytes);

        // Cooperative grid must be fully co-resident. Query achievable
        // blocks/CU (host-side, capture-safe) and cap at 2048 (= 8/CU x 256 CU).
        int maxB = 0;
        hipError_t qe = hipOccupancyMaxActiveBlocksPerMultiprocessor(
            &maxB, fused_kernel, 256, 0);
        int nblocks = 2048;
        if (qe == hipSuccess && maxB > 0) {
            int cap = maxB * 256;           // 256 CUs on gfx950 (MI355X)
            if (cap < nblocks) nblocks = cap;
        }

        void* args[] = { (void*)&feats, (void*)&idx, (void*)&head,
                         (void*)&next, (void*)&out, (void*)&n_active };
        hipError_t le = hipLaunchCooperativeKernel(
            fused_kernel, dim3(nblocks), dim3(256), args, 0, stream);

        if (le != hipSuccess) {
            // Fallback: R7 3-kernel path.
            init_head_kernel<<<(N_SITES_TOTAL + 255) / 256, 256, 0, stream>>>(head, N_SITES_TOTAL);
            build_chains_kernel<<<(n_active + 255) / 256, 256, 0, stream>>>(idx, head, next, n_active);
            gather_kernel<<<(2 * N_SITES_TOTAL) / 256, 256, 0, stream>>>(feats, head, next, out);
        }
    } else {
        // fallback: R3 atomic path
        int n4 = out_size >> 2;
        zero_kernel<<<(n4 + 255) / 256, 256, 0, stream>>>((float4*)out, n4);
        int total = n_active * C_CH;
        scatter_atomic_kernel<<<(total + 255) / 256, 256, 0, stream>>>(feats, idx, out, n_active);
    }
}

// Round 3
// 201.765 us; speedup vs baseline: 2.0512x; 2.0512x over previous
//
#include <hip/hip_runtime.h>

// SparseToDense: scatter features [N,32] into dense [B=4, C=32, D=64, H=64, W=64].
// flat_idx (int32 on device) indexes B*D*H*W sites; output is NCDHW. DHW = 2^18.
//
// Strategy (R9b): 3-kernel chain pipeline (R7-proven) + LDS-transposed stores.
//   R8 post-mortem: cooperative fusion with __launch_bounds__(256,8) strangled
//   the kernel to 24 VGPRs -> chain-walk loads serialized (no ILP) -> 362us at
//   5% HBM. REVERTED. Rule: never combine min-waves bounds with an unrolled
//   latency-hiding load body.
//   R9 change: gather epilogue goes through LDS. Before: 16 scalar NT dword
//   stores/thread at 1MB stride -> two 128B segments per wave instr, 32+
//   interleaved scattered write streams at DRAM. Now: block accumulates 128
//   sites, transposes its 128x32 tile in LDS (channel-major, stride 132 ->
//   2-way bank aliasing = free per m136), then streams float4 NT stores:
//   512B contiguous per channel per wave instr, 4 store instrs/thread.
//   R9b fix: __builtin_nontemporal_store requires a clang vector type, not
//   HIP's float4 struct -> use floatx4 (ext_vector_type) for the NT stores.
// Kept from R7: cached loads for feats/head/next (R6 showed NT loads regress);
//   NONTEMPORAL stores (134MB stream must not evict chain data from L2);
//   2 threads/site (half the acc VGPRs, pair lanes split the 128B row).
// Budget (measured R0): init ~2us, build ~19us (400k atomicExch at fabric
//   rate), gather ~75us vs ~30us byte floor -> this round targets the gap.

#define DHW_LOG2 18
#define DHW (1 << DHW_LOG2)
#define C_CH 32
#define N_SITES_TOTAL (4 * DHW)   // B=4 -> 1048576 sites
#define SITES_PER_BLOCK 128       // 256 threads, 2 threads/site
#define LDS_PAD 132               // 128 sites padded: 132%32=4 -> 2-way banks; 16B-aligned rows

typedef float floatx4 __attribute__((ext_vector_type(4)));

__global__ __launch_bounds__(256) void init_head_kernel(int* __restrict__ head, int n)
{
    int t = blockIdx.x * blockDim.x + threadIdx.x;
    if (t < n) head[t] = -1;
}

__global__ __launch_bounds__(256) void build_chains_kernel(
    const int* __restrict__ flat_idx,
    int* __restrict__ head,
    int* __restrict__ next,
    int n_active)
{
    int i = blockIdx.x * blockDim.x + threadIdx.x;
    if (i >= n_active) return;
    int s = flat_idx[i];
    int prev = atomicExch(&head[s], i);   // device-scope int atomic, 4 MB array
    next[i] = prev;
}

__global__ __launch_bounds__(256) void gather_kernel(
    const float* __restrict__ feats,
    const int* __restrict__ head,
    const int* __restrict__ next,
    float* __restrict__ out)
{
    __shared__ __align__(16) float lds[C_CH][LDS_PAD];

    const int t  = threadIdx.x;
    const int sl = t >> 1;        // site within block (lane pairs share a site)
    const int h  = t & 1;         // channel half: channels h*16 .. h*16+15
    const int S0 = blockIdx.x * SITES_PER_BLOCK;
    const int S  = S0 + sl;

    floatx4 a0 = (floatx4)0.f, a1 = (floatx4)0.f, a2 = (floatx4)0.f, a3 = (floatx4)0.f;

    int p = head[S];              // pair lanes broadcast; L2-resident 4 MB
    while (p != -1) {
        const floatx4* row = (const floatx4*)(feats + ((size_t)p * C_CH + h * 16));
        int pn = next[p];                 // issue next-hop early
        floatx4 f0 = row[0];              // cached: 1 line fill + 3 L1 hits / 64B half
        floatx4 f1 = row[1];
        floatx4 f2 = row[2];
        floatx4 f3 = row[3];
        a0 += f0; a1 += f1; a2 += f2; a3 += f3;
        p = pn;
    }

    // Transpose through LDS: lds[c][site_local]. Write banks for fixed j:
    // (4*(h*16+j) + sl) & 31 -> 32 banks, 2 lanes each (2-way = free).
    float acc[16] = {
        a0.x, a0.y, a0.z, a0.w,  a1.x, a1.y, a1.z, a1.w,
        a2.x, a2.y, a2.z, a2.w,  a3.x, a3.y, a3.z, a3.w };
    #pragma unroll
    for (int j = 0; j < 16; ++j)
        lds[h * 16 + j][sl] = acc[j];

    __syncthreads();

    // Stream out: 4096 floats = 1024 float4. q -> (channel, float4-within-channel).
    // Lanes 0-31 of a wave: same channel, i4=0..31 -> 512 B contiguous segment.
    const int b   = S0 >> DHW_LOG2;
    const int sp0 = S0 & (DHW - 1);
    #pragma unroll
    for (int it = 0; it < 4; ++it) {
        int q  = it * 256 + t;
        int c  = q >> 5;          // 0..31
        int i4 = q & 31;          // float4 index within this block's channel run
        floatx4 v = *reinterpret_cast<const floatx4*>(&lds[c][i4 * 4]);
        floatx4* o = reinterpret_cast<floatx4*>(
            out + (((size_t)(b * C_CH + c)) << DHW_LOG2) + sp0 + i4 * 4);
        __builtin_nontemporal_store(v, o);
    }
}

// ---- fallback (R3 behavior) if workspace is too small ----
__global__ __launch_bounds__(256) void zero_kernel(float4* __restrict__ out, int n4)
{
    int t = blockIdx.x * blockDim.x + threadIdx.x;
    if (t < n4) out[t] = make_float4(0.f, 0.f, 0.f, 0.f);
}

__global__ __launch_bounds__(256) void scatter_atomic_kernel(
    const float* __restrict__ feats,
    const int* __restrict__ flat_idx,
    float* __restrict__ out,
    int n_active)
{
    int t = blockIdx.x * blockDim.x + threadIdx.x;
    int i = t >> 5, c = t & 31;
    if (i >= n_active) return;
    int s = flat_idx[i];
    atomicAdd(&out[(((size_t)(s >> DHW_LOG2) * C_CH + c) << DHW_LOG2) + (s & (DHW - 1))],
              feats[(size_t)i * C_CH + c]);
}

extern "C" void kernel_launch(void* const* d_in, const int* in_sizes, int n_in,
                              void* d_out, int out_size, void* d_ws, size_t ws_size,
                              hipStream_t stream) {
    const float* feats = (const float*)d_in[0];
    const int*   idx   = (const int*)d_in[1];
    float*       out   = (float*)d_out;
    int n_active = in_sizes[1];   // 400000

    size_t head_bytes = (size_t)N_SITES_TOTAL * sizeof(int);      // 4 MB
    size_t next_bytes = (size_t)n_active * sizeof(int);           // 1.6 MB

    if (ws_size >= head_bytes + next_bytes) {
        int* head = (int*)d_ws;
        int* next = (int*)((char*)d_ws + head_bytes);

        init_head_kernel<<<(N_SITES_TOTAL + 255) / 256, 256, 0, stream>>>(head, N_SITES_TOTAL);
        build_chains_kernel<<<(n_active + 255) / 256, 256, 0, stream>>>(idx, head, next, n_active);
        // 8192 blocks x 256 threads; each block owns 128 consecutive sites
        // (never straddles a batch boundary: DHW % 128 == 0).
        gather_kernel<<<N_SITES_TOTAL / SITES_PER_BLOCK, 256, 0, stream>>>(feats, head, next, out);
    } else {
        // fallback: R3 atomic path
        int n4 = out_size >> 2;
        zero_kernel<<<(n4 + 255) / 256, 256, 0, stream>>>((float4*)out, n4);
        int total = n_active * C_CH;
        scatter_atomic_kernel<<<(total + 255) / 256, 256, 0, stream>>>(feats, idx, out, n_active);
    }
}